// Round 1
// baseline (2159.142 us; speedup 1.0000x reference)
//
#include <hip/hip_runtime.h>
#include <math.h>

#define Dm 128
#define Ssz 120
#define Bsz 16
#define Tcy 8
#define Hh 4
#define DA 32
#define Lly 2
#define RT 8           // rows per block tile (120 % 8 == 0)
#define NROWB ((Bsz*Ssz)/RT)   // 240 row-tile blocks

struct KParams {
    const float *meas, *event_, *leak, *event_leak, *bias;
    const float *pm_w, *pm_b, *pe_w, *pe_b, *pl_w, *pl_b, *pel_w, *pel_b;
    const float *stab_emb, *cyc_emb;
    const float *er_ln_s, *er_ln_b, *er_fc1_w, *er_fc1_b, *er_fc2_w, *er_fc2_b;
    const float *ln1_s, *ln1_b, *Wb, *Wq, *bq, *Wk, *bk, *Wv, *bv, *Wo, *bo;
    const float *ln2_s, *ln2_b, *f1_w, *f1_b, *f2_w, *f2_b, *conv_w, *conv_b;
    const float *lnf_s, *lnf_b, *Pp, *sc_w, *sc_b, *dr_w, *dr_b;
    const float *rb1_w, *rb1_b, *rb2_w, *rb2_b, *out_w, *out_b;
    const int *stab_ids, *cycle_ids;
    float *Bp, *Q, *K, *V, *O, *G, *Y2, *tmp, *cwT;
};

__device__ __forceinline__ float gelu_f(float x) {
    return 0.5f * x * (1.0f + erff(x * 0.70710678118654752f));
}

// LayerNorm stats for RT=8 rows held in LDS [RT][Dm], 16 threads per row.
__device__ __forceinline__ void row_stats8(const float (*arr)[Dm], float* mu, float* rs, int tid) {
    int r = tid >> 4, g = tid & 15;
    float s1 = 0.f;
#pragma unroll
    for (int k = 0; k < 8; k++) s1 += arr[r][g + 16 * k];
#pragma unroll
    for (int off = 8; off; off >>= 1) s1 += __shfl_xor(s1, off);
    float m = s1 * (1.f / 128.f);
    float s2 = 0.f;
#pragma unroll
    for (int k = 0; k < 8; k++) { float d = arr[r][g + 16 * k] - m; s2 += d * d; }
#pragma unroll
    for (int off = 8; off; off >>= 1) s2 += __shfl_xor(s2, off);
    if (g == 0) { mu[r] = m; rs[r] = rsqrtf(s2 * (1.f / 128.f) + 1e-5f); }
}

// ---- transpose conv_w (L,O,I,3) -> cwT (L,I,3,O) for coalesced reads ----
__global__ __launch_bounds__(256) void k_prepcw(KParams p) {
    int idx = blockIdx.x * 256 + threadIdx.x;
    if (idx >= Lly * Dm * 3 * Dm) return;
    int o = idx & 127; int rest = idx >> 7;
    int k = rest % 3; rest /= 3;
    int i = rest & 127; int l = rest >> 7;
    p.cwT[idx] = p.conv_w[((l * Dm + o) * Dm + i) * 3 + k];
}

// ---- Bp[l,b,h,i,j] = sum_c bias[b,i,j,c] * Wb[l,c,h] ----
__global__ __launch_bounds__(128) void k_bias(KParams p) {
    int blk = blockIdx.x;                    // l*(B*S) + b*S + i
    int l = blk / (Bsz * Ssz); int rem = blk % (Bsz * Ssz);
    int b = rem / Ssz, i = rem % Ssz;
    int j = threadIdx.x;
    if (j >= Ssz) return;
    const float* br = p.bias + ((size_t)(b * Ssz + i) * Ssz + j) * 32;
    float a0 = 0.f, a1 = 0.f, a2 = 0.f, a3 = 0.f;
#pragma unroll 8
    for (int c = 0; c < 32; c++) {
        float bv = br[c];
        const float* w = p.Wb + (l * 32 + c) * Hh;
        a0 += bv * w[0]; a1 += bv * w[1]; a2 += bv * w[2]; a3 += bv * w[3];
    }
    size_t base = (((size_t)(l * Bsz + b) * Hh) * Ssz + i) * Ssz + j;
    size_t hs = (size_t)Ssz * Ssz;
    p.Bp[base] = a0; p.Bp[base + hs] = a1; p.Bp[base + 2 * hs] = a2; p.Bp[base + 3 * hs] = a3;
}

// ---- embed(t) + X = (X + h)/sqrt(2) ----
__global__ __launch_bounds__(128) void k_embed(KParams p, float* X, int t) {
    __shared__ float h[RT][Dm], hn[RT][Dm], t1[RT][Dm];
    __shared__ float mu[RT], rs[RT];
    int row0 = blockIdx.x * RT;
    int b = row0 / Ssz, s0 = row0 % Ssz;
    int j = threadIdx.x;
    int cid = p.cycle_ids[t];
    float cycv = p.cyc_emb[cid * Dm + j];
#pragma unroll
    for (int r = 0; r < RT; r++) {
        int s = s0 + r;
        int sid = p.stab_ids[s];
        int mi = (b * Tcy + t) * Ssz + s;
        h[r][j] = p.meas[mi] * p.pm_w[j] + p.pm_b[j]
                + p.event_[mi] * p.pe_w[j] + p.pe_b[j]
                + p.leak[mi] * p.pl_w[j] + p.pl_b[j]
                + p.event_leak[mi] * p.pel_w[j] + p.pel_b[j]
                + p.stab_emb[sid * Dm + j] + cycv;
    }
    __syncthreads();
    for (int rb = 0; rb < 2; rb++) {
        row_stats8(h, mu, rs, j);
        __syncthreads();
        const float* lns = p.er_ln_s + rb * Dm;
        const float* lnb = p.er_ln_b + rb * Dm;
#pragma unroll
        for (int r = 0; r < RT; r++) hn[r][j] = (h[r][j] - mu[r]) * rs[r] * lns[j] + lnb[j];
        __syncthreads();
        const float* W1 = p.er_fc1_w + rb * Dm * Dm;
        float acc[RT];
#pragma unroll
        for (int r = 0; r < RT; r++) acc[r] = 0.f;
        for (int i = 0; i < Dm; i++) {
            float w = W1[i * Dm + j];
#pragma unroll
            for (int r = 0; r < RT; r++) acc[r] += hn[r][i] * w;
        }
        float b1 = p.er_fc1_b[rb * Dm + j];
#pragma unroll
        for (int r = 0; r < RT; r++) t1[r][j] = gelu_f(acc[r] + b1);
        __syncthreads();
        const float* W2 = p.er_fc2_w + rb * Dm * Dm;
#pragma unroll
        for (int r = 0; r < RT; r++) acc[r] = 0.f;
        for (int i = 0; i < Dm; i++) {
            float w = W2[i * Dm + j];
#pragma unroll
            for (int r = 0; r < RT; r++) acc[r] += t1[r][i] * w;
        }
        float b2 = p.er_fc2_b[rb * Dm + j];
#pragma unroll
        for (int r = 0; r < RT; r++) h[r][j] += acc[r] + b2;
        __syncthreads();
    }
    const float inv = 0.70710678118654752f;
#pragma unroll
    for (int r = 0; r < RT; r++) {
        int idx = (row0 + r) * Dm + j;
        X[idx] = (X[idx] + h[r][j]) * inv;
    }
}

// ---- ln1 + Q,K,V projections ----
__global__ __launch_bounds__(128) void k_qkv(KParams p, const float* X, int l) {
    __shared__ float xn[RT][Dm];
    __shared__ float mu[RT], rs[RT];
    int row0 = blockIdx.x * RT;
    int b = row0 / Ssz, s0 = row0 % Ssz;
    int j = threadIdx.x;
#pragma unroll
    for (int r = 0; r < RT; r++) xn[r][j] = X[(row0 + r) * Dm + j];
    __syncthreads();
    row_stats8(xn, mu, rs, j);
    __syncthreads();
    const float* lns = p.ln1_s + l * Dm;
    const float* lnb = p.ln1_b + l * Dm;
#pragma unroll
    for (int r = 0; r < RT; r++) xn[r][j] = (xn[r][j] - mu[r]) * rs[r] * lns[j] + lnb[j];
    __syncthreads();
    int h = j >> 5, e = j & 31;
    float acc[RT];
    // Q
    {
        const float* W = p.Wq + (size_t)((l * Hh + h) * Dm) * DA + e;
#pragma unroll
        for (int r = 0; r < RT; r++) acc[r] = 0.f;
        for (int i = 0; i < Dm; i++) {
            float w = W[i * DA];
#pragma unroll
            for (int r = 0; r < RT; r++) acc[r] += xn[r][i] * w;
        }
        float bb = p.bq[(l * Hh + h) * DA + e];
#pragma unroll
        for (int r = 0; r < RT; r++)
            p.Q[((size_t)(b * Hh + h) * Ssz + s0 + r) * DA + e] = acc[r] + bb;
    }
    // K
    {
        const float* W = p.Wk + (size_t)((l * Hh + h) * Dm) * DA + e;
#pragma unroll
        for (int r = 0; r < RT; r++) acc[r] = 0.f;
        for (int i = 0; i < Dm; i++) {
            float w = W[i * DA];
#pragma unroll
            for (int r = 0; r < RT; r++) acc[r] += xn[r][i] * w;
        }
        float bb = p.bk[(l * Hh + h) * DA + e];
#pragma unroll
        for (int r = 0; r < RT; r++)
            p.K[((size_t)(b * Hh + h) * Ssz + s0 + r) * DA + e] = acc[r] + bb;
    }
    // V
    {
        const float* W = p.Wv + (size_t)((l * Hh + h) * Dm) * DA + e;
#pragma unroll
        for (int r = 0; r < RT; r++) acc[r] = 0.f;
        for (int i = 0; i < Dm; i++) {
            float w = W[i * DA];
#pragma unroll
            for (int r = 0; r < RT; r++) acc[r] += xn[r][i] * w;
        }
        float bb = p.bv[(l * Hh + h) * DA + e];
#pragma unroll
        for (int r = 0; r < RT; r++)
            p.V[((size_t)(b * Hh + h) * Ssz + s0 + r) * DA + e] = acc[r] + bb;
    }
}

// ---- attention: scores + bias, softmax, PV.  grid = B*H*15, 8 q-rows/block ----
__global__ __launch_bounds__(128) void k_attn(KParams p, int l) {
    __shared__ float q[RT][DA];
    __shared__ float sc[RT][128];
    __shared__ float mx[RT], dn[RT];
    int blk = blockIdx.x;
    int bh = blk / (Ssz / RT), qt = blk % (Ssz / RT);
    int q0 = qt * RT;
    int b = bh / Hh, h = bh % Hh;
    int j = threadIdx.x;
    {
        int r = j >> 5, e = j & 31;        // 128 threads = 4 rows x 32
#pragma unroll
        for (int rr = r; rr < RT; rr += 4)
            q[rr][e] = p.Q[((size_t)bh * Ssz + q0 + rr) * DA + e];
    }
    __syncthreads();
    float acc[RT];
#pragma unroll
    for (int r = 0; r < RT; r++) acc[r] = 0.f;
    if (j < Ssz) {
        const float* Kr = p.K + ((size_t)bh * Ssz + j) * DA;
        for (int e = 0; e < DA; e++) {
            float kv = Kr[e];
#pragma unroll
            for (int r = 0; r < RT; r++) acc[r] += q[r][e] * kv;
        }
    }
    const float scale = 0.17677669529663689f;    // 1/sqrt(32)
    const float* Bpr = p.Bp + (((size_t)(l * Bsz + b) * Hh + h) * Ssz + q0) * Ssz;
#pragma unroll
    for (int r = 0; r < RT; r++)
        sc[r][j] = (j < Ssz) ? (acc[r] + Bpr[r * Ssz + j]) * scale : -1e30f;
    __syncthreads();
    {
        int r = j >> 4, g = j & 15;
        float m = -1e30f;
#pragma unroll
        for (int k = 0; k < 8; k++) m = fmaxf(m, sc[r][g + 16 * k]);
#pragma unroll
        for (int off = 8; off; off >>= 1) m = fmaxf(m, __shfl_xor(m, off));
        if (g == 0) mx[r] = m;
    }
    __syncthreads();
#pragma unroll
    for (int r = 0; r < RT; r++) sc[r][j] = (j < Ssz) ? expf(sc[r][j] - mx[r]) : 0.f;
    __syncthreads();
    {
        int r = j >> 4, g = j & 15;
        float s1 = 0.f;
#pragma unroll
        for (int k = 0; k < 8; k++) s1 += sc[r][g + 16 * k];
#pragma unroll
        for (int off = 8; off; off >>= 1) s1 += __shfl_xor(s1, off);
        if (g == 0) dn[r] = s1;
    }
    __syncthreads();
    int m = j & 31, rg = j >> 5;                 // 4 row-groups, each handles rows rg, rg+4
    float a0 = 0.f, a1 = 0.f;
    const float* Vb = p.V + (size_t)bh * Ssz * DA + m;
    for (int k2 = 0; k2 < Ssz; k2++) {
        float v = Vb[k2 * DA];
        a0 += sc[rg][k2] * v;
        a1 += sc[rg + 4][k2] * v;
    }
    p.O[((size_t)bh * Ssz + q0 + rg) * DA + m] = a0 / dn[rg];
    p.O[((size_t)bh * Ssz + q0 + rg + 4) * DA + m] = a1 / dn[rg + 4];
}

// ---- X += Y * Wo + bo ----
__global__ __launch_bounds__(128) void k_oproj(KParams p, float* X, int l) {
    __shared__ float y[RT][Dm];
    int row0 = blockIdx.x * RT;
    int b = row0 / Ssz, s0 = row0 % Ssz;
    int j = threadIdx.x;
    int h = j >> 5, m = j & 31;
#pragma unroll
    for (int r = 0; r < RT; r++)
        y[r][j] = p.O[((size_t)(b * Hh + h) * Ssz + s0 + r) * DA + m];
    __syncthreads();
    float acc[RT];
#pragma unroll
    for (int r = 0; r < RT; r++) acc[r] = 0.f;
    const float* W = p.Wo + l * Dm * Dm + j;
    for (int k = 0; k < Dm; k++) {
        float w = W[k * Dm];
#pragma unroll
        for (int r = 0; r < RT; r++) acc[r] += y[r][k] * w;
    }
    float bb = p.bo[l * Dm + j];
#pragma unroll
    for (int r = 0; r < RT; r++) X[(row0 + r) * Dm + j] += acc[r] + bb;
}

// ---- ln2 + gated FFN ----
__global__ __launch_bounds__(128) void k_ffn(KParams p, float* X, int l) {
    __shared__ float xn[RT][Dm];
    __shared__ float yf[RT][512];
    __shared__ float mu[RT], rs[RT];
    int row0 = blockIdx.x * RT;
    int j = threadIdx.x;
#pragma unroll
    for (int r = 0; r < RT; r++) xn[r][j] = X[(row0 + r) * Dm + j];
    __syncthreads();
    row_stats8(xn, mu, rs, j);
    __syncthreads();
    const float* lns = p.ln2_s + l * Dm;
    const float* lnb = p.ln2_b + l * Dm;
#pragma unroll
    for (int r = 0; r < RT; r++) xn[r][j] = (xn[r][j] - mu[r]) * rs[r] * lns[j] + lnb[j];
    __syncthreads();
    for (int cg = 0; cg < 4; cg++) {
        int col = cg * 128 + j;
        float acc[RT];
#pragma unroll
        for (int r = 0; r < RT; r++) acc[r] = 0.f;
        const float* W1 = p.f1_w + (size_t)l * Dm * 512 + col;
        for (int i = 0; i < Dm; i++) {
            float w = W1[i * 512];
#pragma unroll
            for (int r = 0; r < RT; r++) acc[r] += xn[r][i] * w;
        }
        float b1 = p.f1_b[l * 512 + col];
#pragma unroll
        for (int r = 0; r < RT; r++) yf[r][col] = acc[r] + b1;
    }
    __syncthreads();
#pragma unroll
    for (int r = 0; r < RT; r++) {
        for (int kk = j; kk < 256; kk += 128) {
            float a = yf[r][kk], g = yf[r][kk + 256];
            yf[r][kk] = gelu_f(a) * g;
        }
    }
    __syncthreads();
    float acc[RT];
#pragma unroll
    for (int r = 0; r < RT; r++) acc[r] = 0.f;
    const float* W2 = p.f2_w + (size_t)l * 256 * Dm + j;
    for (int k = 0; k < 256; k++) {
        float w = W2[k * Dm];
#pragma unroll
        for (int r = 0; r < RT; r++) acc[r] += yf[r][k] * w;
    }
    float b2 = p.f2_b[l * Dm + j];
#pragma unroll
    for (int r = 0; r < RT; r++) X[(row0 + r) * Dm + j] += acc[r] + b2;
}

// ---- conv(k=3, SAME) over stabilizer axis; Xout = Xin + gelu(conv + b) ----
__global__ __launch_bounds__(128) void k_conv(KParams p, const float* Xin, float* Xout, int l) {
    __shared__ float xr[RT + 2][Dm];
    int row0 = blockIdx.x * RT;
    int b = row0 / Ssz, s0 = row0 % Ssz;
    int j = threadIdx.x;
#pragma unroll
    for (int rr = 0; rr < RT + 2; rr++) {
        int s = s0 + rr - 1;
        xr[rr][j] = (s >= 0 && s < Ssz) ? Xin[(b * Ssz + s) * Dm + j] : 0.f;
    }
    __syncthreads();
    float acc[RT];
#pragma unroll
    for (int r = 0; r < RT; r++) acc[r] = 0.f;
    const float* CW = p.cwT + (size_t)l * Dm * 3 * Dm + j;   // [i][k][o], o=j
    for (int i = 0; i < Dm; i++) {
        float w0 = CW[(i * 3 + 0) * Dm];
        float w1 = CW[(i * 3 + 1) * Dm];
        float w2 = CW[(i * 3 + 2) * Dm];
#pragma unroll
        for (int r = 0; r < RT; r++)
            acc[r] += w0 * xr[r][i] + w1 * xr[r + 1][i] + w2 * xr[r + 2][i];
    }
    float cb = p.conv_b[l * Dm + j];
#pragma unroll
    for (int r = 0; r < RT; r++)
        Xout[(row0 + r) * Dm + j] = xr[r + 1][j] + gelu_f(acc[r] + cb);
}

// ---- readout: lnf + pad into 12x12 grid ----
__global__ __launch_bounds__(128) void k_grid(KParams p, const float* X) {
    int blk = blockIdx.x; int b = blk / 144, cell = blk % 144;
    int j = threadIdx.x;
    float* Gr = p.G + (size_t)(b * 144 + cell) * Dm;
    if (cell >= Ssz) { Gr[j] = p.Pp[j]; return; }
    __shared__ float red[4];
    float x = X[(b * Ssz + cell) * Dm + j];
    float s1 = x;
#pragma unroll
    for (int off = 32; off; off >>= 1) s1 += __shfl_xor(s1, off);
    if ((j & 63) == 0) red[j >> 6] = s1;
    __syncthreads();
    float m = (red[0] + red[1]) * (1.f / 128.f);
    float d0 = x - m, s2 = d0 * d0;
#pragma unroll
    for (int off = 32; off; off >>= 1) s2 += __shfl_xor(s2, off);
    if ((j & 63) == 0) red[2 + (j >> 6)] = s2;
    __syncthreads();
    float v = (red[2] + red[3]) * (1.f / 128.f);
    Gr[j] = d0 * rsqrtf(v + 1e-5f) * p.lnf_s[j] + p.lnf_b[j];
}

// ---- scale-conv 2x2/2 + gelu + dim-reduce + gelu -> Y2[b][ow][oh][r] ----
__global__ __launch_bounds__(128) void k_head(KParams p) {
    int blk = blockIdx.x; int b = blk / 36, r2 = blk % 36, oh = r2 / 6, ow = r2 % 6;
    __shared__ float cells[4][Dm];
    __shared__ float sx[Dm];
    int j = threadIdx.x;
#pragma unroll
    for (int c = 0; c < 4; c++) {
        int kh = c >> 1, kw = c & 1;
        int cell = (2 * oh + kh) * 12 + (2 * ow + kw);
        cells[c][j] = p.G[(size_t)(b * 144 + cell) * Dm + j];
    }
    __syncthreads();
    float acc = p.sc_b[j];
    const float* W = p.sc_w + (size_t)j * Dm * 4;   // [o=j][i][kh][kw]
    for (int i = 0; i < Dm; i++) {
        acc += W[i * 4 + 0] * cells[0][i] + W[i * 4 + 1] * cells[1][i]
             + W[i * 4 + 2] * cells[2][i] + W[i * 4 + 3] * cells[3][i];
    }
    sx[j] = gelu_f(acc);
    __syncthreads();
    if (j < 48) {
        float a = p.dr_b[j];
        const float* w = p.dr_w + j * Dm;
        for (int i = 0; i < Dm; i++) a += sx[i] * w[i];
        p.Y2[((b * 6 + ow) * 6 + oh) * 48 + j] = gelu_f(a);
    }
}

// ---- mean over oh + 16 resblocks + out_w dot ----
__global__ __launch_bounds__(64) void k_rb(KParams p) {
    int blk = blockIdx.x; int b = blk / 6, ow = blk % 6;
    __shared__ float x[48], t[48];
    int j = threadIdx.x;
    if (j < 48) {
        float s = 0.f;
#pragma unroll
        for (int oh = 0; oh < 6; oh++) s += p.Y2[((b * 6 + ow) * 6 + oh) * 48 + j];
        x[j] = s * (1.f / 6.f);
    }
    __syncthreads();
    for (int r = 0; r < 16; r++) {
        if (j < 48) {
            float a = p.rb1_b[r * 48 + j];
            const float* W = p.rb1_w + (size_t)r * 48 * 48 + j;
            for (int i = 0; i < 48; i++) a += x[i] * W[i * 48];
            t[j] = gelu_f(a);
        }
        __syncthreads();
        if (j < 48) {
            float a = p.rb2_b[r * 48 + j];
            const float* W = p.rb2_w + (size_t)r * 48 * 48 + j;
            for (int i = 0; i < 48; i++) a += t[i] * W[i * 48];
            x[j] += a;
        }
        __syncthreads();
    }
    float pr = (j < 48) ? x[j] * p.out_w[j] : 0.f;
#pragma unroll
    for (int off = 32; off; off >>= 1) pr += __shfl_xor(pr, off);
    if (j == 0) p.tmp[b * 6 + ow] = pr + p.out_b[0];
}

__global__ __launch_bounds__(64) void k_final(KParams p, float* out) {
    int b = threadIdx.x;
    if (b < Bsz) {
        float s = 0.f;
#pragma unroll
        for (int w = 0; w < 6; w++) s += p.tmp[b * 6 + w];
        out[b] = s * (1.f / 6.f);
    }
}

extern "C" void kernel_launch(void* const* d_in, const int* in_sizes, int n_in,
                              void* d_out, int out_size, void* d_ws, size_t ws_size,
                              hipStream_t stream) {
    KParams p;
    p.meas       = (const float*)d_in[0];
    p.event_     = (const float*)d_in[1];
    p.leak       = (const float*)d_in[2];
    p.event_leak = (const float*)d_in[3];
    p.bias       = (const float*)d_in[4];
    p.pm_w  = (const float*)d_in[5];  p.pm_b  = (const float*)d_in[6];
    p.pe_w  = (const float*)d_in[7];  p.pe_b  = (const float*)d_in[8];
    p.pl_w  = (const float*)d_in[9];  p.pl_b  = (const float*)d_in[10];
    p.pel_w = (const float*)d_in[11]; p.pel_b = (const float*)d_in[12];
    p.stab_emb = (const float*)d_in[13];
    p.cyc_emb  = (const float*)d_in[14];
    p.er_ln_s  = (const float*)d_in[15]; p.er_ln_b  = (const float*)d_in[16];
    p.er_fc1_w = (const float*)d_in[17]; p.er_fc1_b = (const float*)d_in[18];
    p.er_fc2_w = (const float*)d_in[19]; p.er_fc2_b = (const float*)d_in[20];
    p.ln1_s = (const float*)d_in[21]; p.ln1_b = (const float*)d_in[22];
    p.Wb = (const float*)d_in[23];
    p.Wq = (const float*)d_in[24]; p.bq = (const float*)d_in[25];
    p.Wk = (const float*)d_in[26]; p.bk = (const float*)d_in[27];
    p.Wv = (const float*)d_in[28]; p.bv = (const float*)d_in[29];
    p.Wo = (const float*)d_in[30]; p.bo = (const float*)d_in[31];
    p.ln2_s = (const float*)d_in[32]; p.ln2_b = (const float*)d_in[33];
    p.f1_w = (const float*)d_in[34]; p.f1_b = (const float*)d_in[35];
    p.f2_w = (const float*)d_in[36]; p.f2_b = (const float*)d_in[37];
    p.conv_w = (const float*)d_in[38]; p.conv_b = (const float*)d_in[39];
    p.lnf_s = (const float*)d_in[40]; p.lnf_b = (const float*)d_in[41];
    p.Pp   = (const float*)d_in[42];
    p.sc_w = (const float*)d_in[43]; p.sc_b = (const float*)d_in[44];
    p.dr_w = (const float*)d_in[45]; p.dr_b = (const float*)d_in[46];
    p.rb1_w = (const float*)d_in[47]; p.rb1_b = (const float*)d_in[48];
    p.rb2_w = (const float*)d_in[49]; p.rb2_b = (const float*)d_in[50];
    p.out_w = (const float*)d_in[51]; p.out_b = (const float*)d_in[52];
    p.stab_ids  = (const int*)d_in[53];
    p.cycle_ids = (const int*)d_in[54];

    float* ws = (float*)d_ws;
    size_t off = 0;
    const size_t BP_SZ  = (size_t)Lly * Bsz * Hh * Ssz * Ssz;   // 1,843,200
    const size_t QKV_SZ = (size_t)Bsz * Hh * Ssz * DA;          //   245,760
    const size_t X_SZ   = (size_t)Bsz * Ssz * Dm;               //   245,760
    p.Bp = ws + off; off += BP_SZ;
    p.Q  = ws + off; off += QKV_SZ;
    p.K  = ws + off; off += QKV_SZ;
    p.V  = ws + off; off += QKV_SZ;
    p.O  = ws + off; off += QKV_SZ;
    float* X0 = ws + off; off += X_SZ;
    float* X1 = ws + off; off += X_SZ;
    p.G   = ws + off; off += (size_t)Bsz * 144 * Dm;            //   294,912
    p.Y2  = ws + off; off += (size_t)Bsz * 6 * 6 * 48;          //    27,648
    p.tmp = ws + off; off += 96;
    p.cwT = ws + off; off += (size_t)Lly * Dm * 3 * Dm;         //    98,304

    hipMemsetAsync(X0, 0, X_SZ * sizeof(float), stream);
    k_prepcw<<<(Lly * Dm * 3 * Dm + 255) / 256, 256, 0, stream>>>(p);
    k_bias<<<Lly * Bsz * Ssz, 128, 0, stream>>>(p);

    float* Xc = X0;
    float* Xa = X1;
    for (int t = 0; t < Tcy; t++) {
        k_embed<<<NROWB, 128, 0, stream>>>(p, Xc, t);
        for (int l = 0; l < Lly; l++) {
            k_qkv<<<NROWB, 128, 0, stream>>>(p, Xc, l);
            k_attn<<<Bsz * Hh * (Ssz / RT), 128, 0, stream>>>(p, l);
            k_oproj<<<NROWB, 128, 0, stream>>>(p, Xc, l);
            k_ffn<<<NROWB, 128, 0, stream>>>(p, Xc, l);
            k_conv<<<NROWB, 128, 0, stream>>>(p, Xc, Xa, l);
            float* tp = Xc; Xc = Xa; Xa = tp;
        }
    }
    k_grid<<<Bsz * 144, 128, 0, stream>>>(p, Xc);
    k_head<<<Bsz * 36, 128, 0, stream>>>(p);
    k_rb<<<Bsz * 6, 64, 0, stream>>>(p);
    k_final<<<1, 64, 0, stream>>>(p, (float*)d_out);
}

// Round 2
// 1529.952 us; speedup vs baseline: 1.4112x; 1.4112x over previous
//
#include <hip/hip_runtime.h>
#include <math.h>

#define Dm 128
#define Ssz 120
#define Bsz 16
#define Tcy 8
#define Hh 4
#define DA 32
#define Lly 2
#define RT 4                    // rows per block tile (120 % 4 == 0)
#define NRT ((Bsz*Ssz)/RT)      // 480 row-tile blocks

struct KParams {
    const float *meas, *event_, *leak, *event_leak, *bias;
    const float *pm_w, *pm_b, *pe_w, *pe_b, *pl_w, *pl_b, *pel_w, *pel_b;
    const float *stab_emb, *cyc_emb;
    const float *er_ln_s, *er_ln_b, *er_fc1_w, *er_fc1_b, *er_fc2_w, *er_fc2_b;
    const float *ln1_s, *ln1_b, *Wb, *Wq, *bq, *Wk, *bk, *Wv, *bv, *Wo, *bo;
    const float *ln2_s, *ln2_b, *f1_w, *f1_b, *f2_w, *f2_b, *conv_w, *conv_b;
    const float *lnf_s, *lnf_b, *Pp, *sc_w, *sc_b, *dr_w, *dr_b;
    const float *rb1_w, *rb1_b, *rb2_w, *rb2_b, *out_w, *out_b;
    const int *stab_ids, *cycle_ids;
    float *Bp, *Q, *K, *V, *G, *Y2, *tmp, *cwT;
};

__device__ __forceinline__ float gelu_f(float x) {
    return 0.5f * x * (1.0f + erff(x * 0.70710678118654752f));
}

// LayerNorm 4 rows; wave w handles row w (threads 0..255). src may equal dst.
__device__ __forceinline__ void ln_rows4(const float (*src)[Dm], float (*dst)[Dm],
                                         const float* sg, const float* bg, int tid) {
    int r = tid >> 6, g = tid & 63;
    if (r < 4) {
        float x0 = src[r][g], x1 = src[r][g + 64];
        float s1 = x0 + x1;
#pragma unroll
        for (int off = 32; off; off >>= 1) s1 += __shfl_xor(s1, off);
        float m = s1 * (1.f / 128.f);
        float d0 = x0 - m, d1 = x1 - m;
        float s2 = d0 * d0 + d1 * d1;
#pragma unroll
        for (int off = 32; off; off >>= 1) s2 += __shfl_xor(s2, off);
        float rstd = rsqrtf(s2 * (1.f / 128.f) + 1e-5f);
        dst[r][g]      = d0 * rstd * sg[g]      + bg[g];
        dst[r][g + 64] = d1 * rstd * sg[g + 64] + bg[g + 64];
    }
}

// ---- transpose conv_w (L,O,I,3) -> cwT (L,I,3,O) ----
__global__ __launch_bounds__(256) void k_prepcw(KParams p) {
    int idx = blockIdx.x * 256 + threadIdx.x;
    if (idx >= Lly * Dm * 3 * Dm) return;
    int o = idx & 127; int rest = idx >> 7;
    int k = rest % 3; rest /= 3;
    int i = rest & 127; int l = rest >> 7;
    p.cwT[idx] = p.conv_w[((l * Dm + o) * Dm + i) * 3 + k];
}

// ---- Bp[l,b,h,i,j] = sum_c bias[b,i,j,c] * Wb[l,c,h] ----
__global__ __launch_bounds__(128) void k_bias(KParams p) {
    int blk = blockIdx.x;                    // l*(B*S) + b*S + i
    int l = blk / (Bsz * Ssz); int rem = blk % (Bsz * Ssz);
    int b = rem / Ssz, i = rem % Ssz;
    int j = threadIdx.x;
    if (j >= Ssz) return;
    const float* br = p.bias + ((size_t)(b * Ssz + i) * Ssz + j) * 32;
    float a0 = 0.f, a1 = 0.f, a2 = 0.f, a3 = 0.f;
#pragma unroll 8
    for (int c = 0; c < 32; c++) {
        float bv = br[c];
        const float* w = p.Wb + (l * 32 + c) * Hh;
        a0 += bv * w[0]; a1 += bv * w[1]; a2 += bv * w[2]; a3 += bv * w[3];
    }
    size_t base = (((size_t)(l * Bsz + b) * Hh) * Ssz + i) * Ssz + j;
    size_t hs = (size_t)Ssz * Ssz;
    p.Bp[base] = a0; p.Bp[base + hs] = a1; p.Bp[base + 2 * hs] = a2; p.Bp[base + 3 * hs] = a3;
}

// ---- embed(t) + X = (X + h)/sqrt(2).  grid 480, 256 thr ----
__global__ __launch_bounds__(256) void k_embed(KParams p, float* X, int t) {
    __shared__ float h[RT][Dm], hn[RT][Dm], t1[RT][Dm];
    int row0 = blockIdx.x * RT;
    int b = row0 / Ssz, s0 = row0 % Ssz;
    int tid = threadIdx.x;
    int cid = p.cycle_ids[t];
    for (int i = tid; i < RT * Dm; i += 256) {
        int r = i >> 7, j = i & 127;
        int s = s0 + r;
        int sid = p.stab_ids[s];
        int mi = (b * Tcy + t) * Ssz + s;
        h[r][j] = p.meas[mi] * p.pm_w[j] + p.pm_b[j]
                + p.event_[mi] * p.pe_w[j] + p.pe_b[j]
                + p.leak[mi] * p.pl_w[j] + p.pl_b[j]
                + p.event_leak[mi] * p.pel_w[j] + p.pel_b[j]
                + p.stab_emb[sid * Dm + j] + p.cyc_emb[cid * Dm + j];
    }
    __syncthreads();
    int g = tid >> 7, j = tid & 127;    // g=row-pair, rows 2g, 2g+1
    for (int rb = 0; rb < 2; rb++) {
        ln_rows4(h, hn, p.er_ln_s + rb * Dm, p.er_ln_b + rb * Dm, tid);
        __syncthreads();
        const float* W1 = p.er_fc1_w + rb * Dm * Dm;
        float a0 = 0.f, a1 = 0.f;
        for (int i = 0; i < Dm; i++) {
            float w = W1[i * Dm + j];
            a0 += hn[2 * g][i] * w; a1 += hn[2 * g + 1][i] * w;
        }
        float b1 = p.er_fc1_b[rb * Dm + j];
        t1[2 * g][j] = gelu_f(a0 + b1); t1[2 * g + 1][j] = gelu_f(a1 + b1);
        __syncthreads();
        const float* W2 = p.er_fc2_w + rb * Dm * Dm;
        a0 = 0.f; a1 = 0.f;
        for (int i = 0; i < Dm; i++) {
            float w = W2[i * Dm + j];
            a0 += t1[2 * g][i] * w; a1 += t1[2 * g + 1][i] * w;
        }
        float b2 = p.er_fc2_b[rb * Dm + j];
        h[2 * g][j] += a0 + b2; h[2 * g + 1][j] += a1 + b2;
        __syncthreads();
    }
    const float inv = 0.70710678118654752f;
    for (int i = tid; i < RT * Dm; i += 256) {
        int idx = row0 * Dm + i;
        X[idx] = (X[idx] + h[i >> 7][i & 127]) * inv;
    }
}

// ---- ln1 + Q,K,V projections.  grid 480, 384 thr ----
__global__ __launch_bounds__(384) void k_qkv(KParams p, const float* X, int l) {
    __shared__ float xn[RT][Dm];
    int row0 = blockIdx.x * RT;
    int b = row0 / Ssz, s0 = row0 % Ssz;
    int tid = threadIdx.x;
    for (int i = tid; i < RT * Dm; i += 384) xn[i >> 7][i & 127] = X[row0 * Dm + i];
    __syncthreads();
    ln_rows4(xn, xn, p.ln1_s + l * Dm, p.ln1_b + l * Dm, tid);
    __syncthreads();
    int out = tid >> 7, col = tid & 127;     // out: 0=Q 1=K 2=V
    int h = col >> 5, e = col & 31;
    const float* W = (out == 0 ? p.Wq : out == 1 ? p.Wk : p.Wv)
                   + ((size_t)(l * Hh + h) * Dm) * DA + e;
    const float* bb = (out == 0 ? p.bq : out == 1 ? p.bk : p.bv) + (l * Hh + h) * DA + e;
    float* dst = (out == 0 ? p.Q : out == 1 ? p.K : p.V);
    float a0 = 0.f, a1 = 0.f, a2 = 0.f, a3 = 0.f;
    for (int i = 0; i < Dm; i++) {
        float w = W[i * DA];
        a0 += xn[0][i] * w; a1 += xn[1][i] * w; a2 += xn[2][i] * w; a3 += xn[3][i] * w;
    }
    float bv = bb[0];
    size_t base = ((size_t)(b * Hh + h) * Ssz + s0) * DA + e;
    dst[base]          = a0 + bv;
    dst[base + DA]     = a1 + bv;
    dst[base + 2 * DA] = a2 + bv;
    dst[base + 3 * DA] = a3 + bv;
}

// ---- fused attention + O-proj + ln2 + gated FFN.  grid 480, 256 thr ----
__global__ __launch_bounds__(256) void k_attn_ffn(KParams p, float* X, int l) {
    __shared__ float q[RT][Hh][DA];          // [row][h][e]
    __shared__ float Kh[Ssz][DA + 1];        // padded: stride 33
    __shared__ float Vh[Ssz][DA + 1];
    __shared__ float sc[RT][Ssz];            // probs
    __shared__ float Yt[RT][Dm];             // attention output (concat heads)
    __shared__ float opv[2][RT][DA];         // split-K PV partials
    __shared__ float dn[RT];
    __shared__ float xn[RT][Dm];
    __shared__ float yf[RT][4 * Dm];
    int blk = blockIdx.x;
    int b = blk / (Ssz / RT), qt = blk % (Ssz / RT);
    int q0 = qt * RT;
    int row0 = blk * RT;                     // == b*Ssz + q0
    int tid = threadIdx.x;

    for (int i = tid; i < RT * Hh * DA; i += 256) {
        int r = i >> 7, rest = i & 127, h = rest >> 5, e = rest & 31;
        q[r][h][e] = p.Q[((size_t)(b * Hh + h) * Ssz + q0 + r) * DA + e];
    }
    const float scale = 0.17677669529663689f;   // 1/sqrt(32)

    for (int h = 0; h < Hh; h++) {
        __syncthreads();   // protect Kh/Vh (prev head) and q (first iter)
        for (int i = tid; i < Ssz * DA; i += 256) {
            int k = i >> 5, e = i & 31;
            size_t src = ((size_t)(b * Hh + h) * Ssz) * DA + i;
            Kh[k][e] = p.K[src];
            Vh[k][e] = p.V[src];
        }
        __syncthreads();
        // scores: wave r handles row r, lane c0 covers cols c0, c0+64
        {
            int r = tid >> 6, c0 = tid & 63;
            const float* Bpr = p.Bp + (((size_t)(l * Bsz + b) * Hh + h) * Ssz + q0 + r) * Ssz;
            float d0 = 0.f, d1 = 0.f;
            bool v1 = (c0 + 64) < Ssz;
            for (int e = 0; e < DA; e++) {
                float qv = q[r][h][e];
                d0 += qv * Kh[c0][e];
                if (v1) d1 += qv * Kh[c0 + 64][e];
            }
            d0 = (d0 + Bpr[c0]) * scale;
            d1 = v1 ? (d1 + Bpr[c0 + 64]) * scale : -1e30f;
            float m = fmaxf(d0, d1);
#pragma unroll
            for (int off = 32; off; off >>= 1) m = fmaxf(m, __shfl_xor(m, off));
            float p0 = expf(d0 - m);
            float p1 = v1 ? expf(d1 - m) : 0.f;
            float s = p0 + p1;
#pragma unroll
            for (int off = 32; off; off >>= 1) s += __shfl_xor(s, off);
            sc[r][c0] = p0;
            if (v1) sc[r][c0 + 64] = p1;
            if (c0 == 0) dn[r] = s;
        }
        __syncthreads();
        // PV, split-K in halves of 60
        {
            int half = tid >> 7, r = (tid >> 5) & 3, m = tid & 31;
            float a = 0.f;
            int k0 = half * 60;
            for (int k = k0; k < k0 + 60; k++) a += sc[r][k] * Vh[k][m];
            opv[half][r][m] = a;
        }
        __syncthreads();
        if (tid < 128) {
            int r = (tid >> 5) & 3, m = tid & 31;
            Yt[r][h * DA + m] = (opv[0][r][m] + opv[1][r][m]) / dn[r];
        }
    }
    __syncthreads();
    // O-proj: rows 2g, 2g+1; keep residual in regs
    int g = tid >> 7, j = tid & 127;
    float xv0, xv1;
    {
        const float* W = p.Wo + l * Dm * Dm + j;
        float a0 = 0.f, a1 = 0.f;
        for (int k = 0; k < Dm; k++) {
            float w = W[k * Dm];
            a0 += Yt[2 * g][k] * w; a1 += Yt[2 * g + 1][k] * w;
        }
        float bb = p.bo[l * Dm + j];
        xv0 = X[(row0 + 2 * g) * Dm + j] + a0 + bb;
        xv1 = X[(row0 + 2 * g + 1) * Dm + j] + a1 + bb;
        xn[2 * g][j] = xv0; xn[2 * g + 1][j] = xv1;
    }
    __syncthreads();
    ln_rows4(xn, xn, p.ln2_s + l * Dm, p.ln2_b + l * Dm, tid);
    __syncthreads();
    // FFN f1: 512 cols in 2 groups of 256
    for (int cg = 0; cg < 2; cg++) {
        int col = cg * 256 + tid;
        const float* W1 = p.f1_w + (size_t)l * Dm * 512 + col;
        float a0 = 0.f, a1 = 0.f, a2 = 0.f, a3 = 0.f;
        for (int i = 0; i < Dm; i++) {
            float w = W1[i * 512];
            a0 += xn[0][i] * w; a1 += xn[1][i] * w; a2 += xn[2][i] * w; a3 += xn[3][i] * w;
        }
        float b1 = p.f1_b[l * 512 + col];
        yf[0][col] = a0 + b1; yf[1][col] = a1 + b1; yf[2][col] = a2 + b1; yf[3][col] = a3 + b1;
    }
    __syncthreads();
    for (int i = tid; i < RT * 256; i += 256) {
        int r = i >> 8, k = i & 255;
        yf[r][k] = gelu_f(yf[r][k]) * yf[r][k + 256];
    }
    __syncthreads();
    {
        const float* W2 = p.f2_w + (size_t)l * 256 * Dm + j;
        float a0 = 0.f, a1 = 0.f;
        for (int k = 0; k < 256; k++) {
            float w = W2[k * Dm];
            a0 += yf[2 * g][k] * w; a1 += yf[2 * g + 1][k] * w;
        }
        float b2 = p.f2_b[l * Dm + j];
        X[(row0 + 2 * g) * Dm + j] = xv0 + a0 + b2;
        X[(row0 + 2 * g + 1) * Dm + j] = xv1 + a1 + b2;
    }
}

// ---- conv(k=3, SAME) over stabilizer axis.  grid 480, 256 thr ----
__global__ __launch_bounds__(256) void k_conv(KParams p, const float* Xin, float* Xout, int l) {
    __shared__ float xr[RT + 2][Dm];
    int row0 = blockIdx.x * RT;
    int b = row0 / Ssz, s0 = row0 % Ssz;
    int tid = threadIdx.x;
    for (int i = tid; i < (RT + 2) * Dm; i += 256) {
        int rr = i >> 7, j = i & 127;
        int s = s0 + rr - 1;
        xr[rr][j] = (s >= 0 && s < Ssz) ? Xin[(b * Ssz + s) * Dm + j] : 0.f;
    }
    __syncthreads();
    int g = tid >> 7, j = tid & 127;
    const float* CW = p.cwT + (size_t)l * Dm * 3 * Dm + j;   // [i][k][o], o=j
    float a0 = 0.f, a1 = 0.f;
    for (int i = 0; i < Dm; i++) {
        float w0 = CW[(i * 3 + 0) * Dm];
        float w1 = CW[(i * 3 + 1) * Dm];
        float w2 = CW[(i * 3 + 2) * Dm];
        a0 += w0 * xr[2 * g][i]     + w1 * xr[2 * g + 1][i] + w2 * xr[2 * g + 2][i];
        a1 += w0 * xr[2 * g + 1][i] + w1 * xr[2 * g + 2][i] + w2 * xr[2 * g + 3][i];
    }
    float cb = p.conv_b[l * Dm + j];
    Xout[(row0 + 2 * g) * Dm + j]     = xr[2 * g + 1][j] + gelu_f(a0 + cb);
    Xout[(row0 + 2 * g + 1) * Dm + j] = xr[2 * g + 2][j] + gelu_f(a1 + cb);
}

// ---- readout: lnf + pad into 12x12 grid ----
__global__ __launch_bounds__(128) void k_grid(KParams p, const float* X) {
    int blk = blockIdx.x; int b = blk / 144, cell = blk % 144;
    int j = threadIdx.x;
    float* Gr = p.G + (size_t)(b * 144 + cell) * Dm;
    if (cell >= Ssz) { Gr[j] = p.Pp[j]; return; }
    __shared__ float red[4];
    float x = X[(b * Ssz + cell) * Dm + j];
    float s1 = x;
#pragma unroll
    for (int off = 32; off; off >>= 1) s1 += __shfl_xor(s1, off);
    if ((j & 63) == 0) red[j >> 6] = s1;
    __syncthreads();
    float m = (red[0] + red[1]) * (1.f / 128.f);
    float d0 = x - m, s2 = d0 * d0;
#pragma unroll
    for (int off = 32; off; off >>= 1) s2 += __shfl_xor(s2, off);
    if ((j & 63) == 0) red[2 + (j >> 6)] = s2;
    __syncthreads();
    float v = (red[2] + red[3]) * (1.f / 128.f);
    Gr[j] = d0 * rsqrtf(v + 1e-5f) * p.lnf_s[j] + p.lnf_b[j];
}

// ---- scale-conv 2x2/2 + gelu + dim-reduce + gelu -> Y2[b][ow][oh][r] ----
__global__ __launch_bounds__(128) void k_head(KParams p) {
    int blk = blockIdx.x; int b = blk / 36, r2 = blk % 36, oh = r2 / 6, ow = r2 % 6;
    __shared__ float cells[4][Dm];
    __shared__ float sx[Dm];
    int j = threadIdx.x;
#pragma unroll
    for (int c = 0; c < 4; c++) {
        int kh = c >> 1, kw = c & 1;
        int cell = (2 * oh + kh) * 12 + (2 * ow + kw);
        cells[c][j] = p.G[(size_t)(b * 144 + cell) * Dm + j];
    }
    __syncthreads();
    float acc = p.sc_b[j];
    const float* W = p.sc_w + (size_t)j * Dm * 4;   // [o=j][i][kh][kw]
    for (int i = 0; i < Dm; i++) {
        acc += W[i * 4 + 0] * cells[0][i] + W[i * 4 + 1] * cells[1][i]
             + W[i * 4 + 2] * cells[2][i] + W[i * 4 + 3] * cells[3][i];
    }
    sx[j] = gelu_f(acc);
    __syncthreads();
    if (j < 48) {
        float a = p.dr_b[j];
        const float* w = p.dr_w + j * Dm;
        for (int i = 0; i < Dm; i++) a += sx[i] * w[i];
        p.Y2[((b * 6 + ow) * 6 + oh) * 48 + j] = gelu_f(a);
    }
}

// ---- mean over oh + 16 resblocks + out_w dot ----
__global__ __launch_bounds__(64) void k_rb(KParams p) {
    int blk = blockIdx.x; int b = blk / 6, ow = blk % 6;
    __shared__ float x[48], t[48];
    int j = threadIdx.x;
    if (j < 48) {
        float s = 0.f;
#pragma unroll
        for (int oh = 0; oh < 6; oh++) s += p.Y2[((b * 6 + ow) * 6 + oh) * 48 + j];
        x[j] = s * (1.f / 6.f);
    }
    __syncthreads();
    for (int r = 0; r < 16; r++) {
        if (j < 48) {
            float a = p.rb1_b[r * 48 + j];
            const float* W = p.rb1_w + (size_t)r * 48 * 48 + j;
            for (int i = 0; i < 48; i++) a += x[i] * W[i * 48];
            t[j] = gelu_f(a);
        }
        __syncthreads();
        if (j < 48) {
            float a = p.rb2_b[r * 48 + j];
            const float* W = p.rb2_w + (size_t)r * 48 * 48 + j;
            for (int i = 0; i < 48; i++) a += t[i] * W[i * 48];
            x[j] += a;
        }
        __syncthreads();
    }
    float pr = (j < 48) ? x[j] * p.out_w[j] : 0.f;
#pragma unroll
    for (int off = 32; off; off >>= 1) pr += __shfl_xor(pr, off);
    if (j == 0) p.tmp[b * 6 + ow] = pr + p.out_b[0];
}

__global__ __launch_bounds__(64) void k_final(KParams p, float* out) {
    int b = threadIdx.x;
    if (b < Bsz) {
        float s = 0.f;
#pragma unroll
        for (int w = 0; w < 6; w++) s += p.tmp[b * 6 + w];
        out[b] = s * (1.f / 6.f);
    }
}

extern "C" void kernel_launch(void* const* d_in, const int* in_sizes, int n_in,
                              void* d_out, int out_size, void* d_ws, size_t ws_size,
                              hipStream_t stream) {
    KParams p;
    p.meas       = (const float*)d_in[0];
    p.event_     = (const float*)d_in[1];
    p.leak       = (const float*)d_in[2];
    p.event_leak = (const float*)d_in[3];
    p.bias       = (const float*)d_in[4];
    p.pm_w  = (const float*)d_in[5];  p.pm_b  = (const float*)d_in[6];
    p.pe_w  = (const float*)d_in[7];  p.pe_b  = (const float*)d_in[8];
    p.pl_w  = (const float*)d_in[9];  p.pl_b  = (const float*)d_in[10];
    p.pel_w = (const float*)d_in[11]; p.pel_b = (const float*)d_in[12];
    p.stab_emb = (const float*)d_in[13];
    p.cyc_emb  = (const float*)d_in[14];
    p.er_ln_s  = (const float*)d_in[15]; p.er_ln_b  = (const float*)d_in[16];
    p.er_fc1_w = (const float*)d_in[17]; p.er_fc1_b = (const float*)d_in[18];
    p.er_fc2_w = (const float*)d_in[19]; p.er_fc2_b = (const float*)d_in[20];
    p.ln1_s = (const float*)d_in[21]; p.ln1_b = (const float*)d_in[22];
    p.Wb = (const float*)d_in[23];
    p.Wq = (const float*)d_in[24]; p.bq = (const float*)d_in[25];
    p.Wk = (const float*)d_in[26]; p.bk = (const float*)d_in[27];
    p.Wv = (const float*)d_in[28]; p.bv = (const float*)d_in[29];
    p.Wo = (const float*)d_in[30]; p.bo = (const float*)d_in[31];
    p.ln2_s = (const float*)d_in[32]; p.ln2_b = (const float*)d_in[33];
    p.f1_w = (const float*)d_in[34]; p.f1_b = (const float*)d_in[35];
    p.f2_w = (const float*)d_in[36]; p.f2_b = (const float*)d_in[37];
    p.conv_w = (const float*)d_in[38]; p.conv_b = (const float*)d_in[39];
    p.lnf_s = (const float*)d_in[40]; p.lnf_b = (const float*)d_in[41];
    p.Pp   = (const float*)d_in[42];
    p.sc_w = (const float*)d_in[43]; p.sc_b = (const float*)d_in[44];
    p.dr_w = (const float*)d_in[45]; p.dr_b = (const float*)d_in[46];
    p.rb1_w = (const float*)d_in[47]; p.rb1_b = (const float*)d_in[48];
    p.rb2_w = (const float*)d_in[49]; p.rb2_b = (const float*)d_in[50];
    p.out_w = (const float*)d_in[51]; p.out_b = (const float*)d_in[52];
    p.stab_ids  = (const int*)d_in[53];
    p.cycle_ids = (const int*)d_in[54];

    float* ws = (float*)d_ws;
    size_t off = 0;
    const size_t BP_SZ  = (size_t)Lly * Bsz * Hh * Ssz * Ssz;   // 1,843,200
    const size_t QKV_SZ = (size_t)Bsz * Hh * Ssz * DA;          //   245,760
    const size_t X_SZ   = (size_t)Bsz * Ssz * Dm;               //   245,760
    p.Bp = ws + off; off += BP_SZ;
    p.Q  = ws + off; off += QKV_SZ;
    p.K  = ws + off; off += QKV_SZ;
    p.V  = ws + off; off += QKV_SZ;
    float* X0 = ws + off; off += X_SZ;
    float* X1 = ws + off; off += X_SZ;
    p.G   = ws + off; off += (size_t)Bsz * 144 * Dm;
    p.Y2  = ws + off; off += (size_t)Bsz * 6 * 6 * 48;
    p.tmp = ws + off; off += 96;
    p.cwT = ws + off; off += (size_t)Lly * Dm * 3 * Dm;

    hipMemsetAsync(X0, 0, X_SZ * sizeof(float), stream);
    k_prepcw<<<(Lly * Dm * 3 * Dm + 255) / 256, 256, 0, stream>>>(p);
    k_bias<<<Lly * Bsz * Ssz, 128, 0, stream>>>(p);

    float* Xc = X0;
    float* Xa = X1;
    for (int t = 0; t < Tcy; t++) {
        k_embed<<<NRT, 256, 0, stream>>>(p, Xc, t);
        for (int l = 0; l < Lly; l++) {
            k_qkv<<<NRT, 384, 0, stream>>>(p, Xc, l);
            k_attn_ffn<<<NRT, 256, 0, stream>>>(p, Xc, l);
            k_conv<<<NRT, 256, 0, stream>>>(p, Xc, Xa, l);
            float* tp = Xc; Xc = Xa; Xa = tp;
        }
    }
    k_grid<<<Bsz * 144, 128, 0, stream>>>(p, Xc);
    k_head<<<Bsz * 36, 128, 0, stream>>>(p);
    k_rb<<<Bsz * 6, 64, 0, stream>>>(p);
    k_final<<<1, 64, 0, stream>>>(p, (float*)d_out);
}

// Round 3
// 1048.722 us; speedup vs baseline: 2.0588x; 1.4589x over previous
//
#include <hip/hip_runtime.h>
#include <math.h>

#define Dm 128
#define Ssz 120
#define Bsz 16
#define Tcy 8
#define Hh 4
#define DA 32
#define Lly 2
#define RT 4                    // rows per block tile (120 % 4 == 0)
#define NRT ((Bsz*Ssz)/RT)      // 480 row-tile blocks

struct KParams {
    const float *meas, *event_, *leak, *event_leak, *bias;
    const float *pm_w, *pm_b, *pe_w, *pe_b, *pl_w, *pl_b, *pel_w, *pel_b;
    const float *stab_emb, *cyc_emb;
    const float *er_ln_s, *er_ln_b, *er_fc1_w, *er_fc1_b, *er_fc2_w, *er_fc2_b;
    const float *ln1_s, *ln1_b, *Wb, *Wq, *bq, *Wk, *bk, *Wv, *bv, *Wo, *bo;
    const float *ln2_s, *ln2_b, *f1_w, *f1_b, *f2_w, *f2_b, *conv_w, *conv_b;
    const float *lnf_s, *lnf_b, *Pp, *sc_w, *sc_b, *dr_w, *dr_b;
    const float *rb1_w, *rb1_b, *rb2_w, *rb2_b, *out_w, *out_b;
    const int *stab_ids, *cycle_ids;
    float *Bp, *Q, *K, *V, *G, *Y2, *tmp, *cwT;
};

__device__ __forceinline__ float gelu_f(float x) {
    return 0.5f * x * (1.0f + erff(x * 0.70710678118654752f));
}

// XCD-pinning swizzle: grid = 16*per_b blocks, dispatch round-robins XCD = i&7.
// Map so XCD x owns batches {2x, 2x+1}; returns linear index b*per_b + j.
__device__ __forceinline__ int swz16(int i, int per_b) {
    return ((((i & 7) << 1) | ((i >> 3) & 1)) * per_b) + (i >> 4);
}

// LayerNorm 4 rows; wave w handles row w. src may equal dst.
__device__ __forceinline__ void ln_rows4(const float (*src)[Dm], float (*dst)[Dm],
                                         const float* sg, const float* bg, int tid) {
    int r = tid >> 6, g = tid & 63;
    if (r < 4) {
        float x0 = src[r][g], x1 = src[r][g + 64];
        float s1 = x0 + x1;
#pragma unroll
        for (int off = 32; off; off >>= 1) s1 += __shfl_xor(s1, off);
        float m = s1 * (1.f / 128.f);
        float d0 = x0 - m, d1 = x1 - m;
        float s2 = d0 * d0 + d1 * d1;
#pragma unroll
        for (int off = 32; off; off >>= 1) s2 += __shfl_xor(s2, off);
        float rstd = rsqrtf(s2 * (1.f / 128.f) + 1e-5f);
        dst[r][g]      = d0 * rstd * sg[g]      + bg[g];
        dst[r][g + 64] = d1 * rstd * sg[g + 64] + bg[g + 64];
    }
}

// ---- transpose conv_w (L,O,I,3) -> cwT (L,I,3,O) ----
__global__ __launch_bounds__(256) void k_prepcw(KParams p) {
    int idx = blockIdx.x * 256 + threadIdx.x;
    if (idx >= Lly * Dm * 3 * Dm) return;
    int o = idx & 127; int rest = idx >> 7;
    int k = rest % 3; rest /= 3;
    int i = rest & 127; int l = rest >> 7;
    p.cwT[idx] = p.conv_w[((l * Dm + o) * Dm + i) * 3 + k];
}

// ---- Bp[l,b,h,i,j] = sum_c bias[b,i,j,c] * Wb[l,c,h] ----
__global__ __launch_bounds__(128) void k_bias(KParams p) {
    int blk = blockIdx.x;                    // l*(B*S) + b*S + i
    int l = blk / (Bsz * Ssz); int rem = blk % (Bsz * Ssz);
    int b = rem / Ssz, i = rem % Ssz;
    int j = threadIdx.x;
    if (j >= Ssz) return;
    const float* br = p.bias + ((size_t)(b * Ssz + i) * Ssz + j) * 32;
    float a0 = 0.f, a1 = 0.f, a2 = 0.f, a3 = 0.f;
#pragma unroll 8
    for (int c = 0; c < 32; c++) {
        float bv = br[c];
        const float* w = p.Wb + (l * 32 + c) * Hh;
        a0 += bv * w[0]; a1 += bv * w[1]; a2 += bv * w[2]; a3 += bv * w[3];
    }
    size_t base = (((size_t)(l * Bsz + b) * Hh) * Ssz + i) * Ssz + j;
    size_t hs = (size_t)Ssz * Ssz;
    p.Bp[base] = a0; p.Bp[base + hs] = a1; p.Bp[base + 2 * hs] = a2; p.Bp[base + 3 * hs] = a3;
}

// ---- embed(t) + X = (X + h)/sqrt(2).  grid 480, 256 thr ----
__global__ __launch_bounds__(256) void k_embed(KParams p, float* X, int t) {
    __shared__ float h[RT][Dm], hn[RT][Dm], t1[RT][Dm];
    int rb = swz16(blockIdx.x, Ssz / RT);
    int row0 = rb * RT;
    int b = row0 / Ssz, s0 = row0 % Ssz;
    int tid = threadIdx.x;
    int cid = p.cycle_ids[t];
    for (int i = tid; i < RT * Dm; i += 256) {
        int r = i >> 7, j = i & 127;
        int s = s0 + r;
        int sid = p.stab_ids[s];
        int mi = (b * Tcy + t) * Ssz + s;
        h[r][j] = p.meas[mi] * p.pm_w[j] + p.pm_b[j]
                + p.event_[mi] * p.pe_w[j] + p.pe_b[j]
                + p.leak[mi] * p.pl_w[j] + p.pl_b[j]
                + p.event_leak[mi] * p.pel_w[j] + p.pel_b[j]
                + p.stab_emb[sid * Dm + j] + p.cyc_emb[cid * Dm + j];
    }
    __syncthreads();
    int g = tid >> 7, j = tid & 127;    // g=row-pair, rows 2g, 2g+1
    for (int rbk = 0; rbk < 2; rbk++) {
        ln_rows4(h, hn, p.er_ln_s + rbk * Dm, p.er_ln_b + rbk * Dm, tid);
        __syncthreads();
        const float* W1 = p.er_fc1_w + rbk * Dm * Dm;
        float a0 = 0.f, a1 = 0.f;
        for (int i = 0; i < Dm; i++) {
            float w = W1[i * Dm + j];
            a0 += hn[2 * g][i] * w; a1 += hn[2 * g + 1][i] * w;
        }
        float b1 = p.er_fc1_b[rbk * Dm + j];
        t1[2 * g][j] = gelu_f(a0 + b1); t1[2 * g + 1][j] = gelu_f(a1 + b1);
        __syncthreads();
        const float* W2 = p.er_fc2_w + rbk * Dm * Dm;
        a0 = 0.f; a1 = 0.f;
        for (int i = 0; i < Dm; i++) {
            float w = W2[i * Dm + j];
            a0 += t1[2 * g][i] * w; a1 += t1[2 * g + 1][i] * w;
        }
        float b2 = p.er_fc2_b[rbk * Dm + j];
        h[2 * g][j] += a0 + b2; h[2 * g + 1][j] += a1 + b2;
        __syncthreads();
    }
    const float inv = 0.70710678118654752f;
    for (int i = tid; i < RT * Dm; i += 256) {
        int idx = row0 * Dm + i;
        X[idx] = (X[idx] + h[i >> 7][i & 127]) * inv;
    }
}

// ---- ln1 + Q,K,V projections.  grid 480, 384 thr ----
__global__ __launch_bounds__(384) void k_qkv(KParams p, const float* X, int l) {
    __shared__ float xn[RT][Dm];
    int rb = swz16(blockIdx.x, Ssz / RT);
    int row0 = rb * RT;
    int b = row0 / Ssz, s0 = row0 % Ssz;
    int tid = threadIdx.x;
    {
        const float4* X4 = (const float4*)(X + row0 * Dm);
        float4* xn4 = (float4*)&xn[0][0];
        for (int i = tid; i < RT * Dm / 4; i += 384) xn4[i] = X4[i];
    }
    __syncthreads();
    ln_rows4(xn, xn, p.ln1_s + l * Dm, p.ln1_b + l * Dm, tid);
    __syncthreads();
    int out = tid >> 7, col = tid & 127;     // out: 0=Q 1=K 2=V
    int h = col >> 5, e = col & 31;
    const float* W = (out == 0 ? p.Wq : out == 1 ? p.Wk : p.Wv)
                   + ((size_t)(l * Hh + h) * Dm) * DA + e;
    const float* bb = (out == 0 ? p.bq : out == 1 ? p.bk : p.bv) + (l * Hh + h) * DA + e;
    float* dst = (out == 0 ? p.Q : out == 1 ? p.K : p.V);
    float a0 = 0.f, a1 = 0.f, a2 = 0.f, a3 = 0.f;
    for (int i = 0; i < Dm; i++) {
        float w = W[i * DA];
        a0 += xn[0][i] * w; a1 += xn[1][i] * w; a2 += xn[2][i] * w; a3 += xn[3][i] * w;
    }
    float bv = bb[0];
    size_t base = ((size_t)(b * Hh + h) * Ssz + s0) * DA + e;
    dst[base]          = a0 + bv;
    dst[base + DA]     = a1 + bv;
    dst[base + 2 * DA] = a2 + bv;
    dst[base + 3 * DA] = a3 + bv;
}

// ---- fused attention + O-proj + ln2 + gated FFN.  grid 480, 256 thr ----
__global__ __launch_bounds__(256) void k_attn_ffn(KParams p, float* X, int l) {
    __shared__ float q[RT][Hh][DA];          // [row][h][e]
    __shared__ float Kh[Ssz][DA + 1];        // padded: stride 33 (conflict-free)
    __shared__ float Vh[Ssz][DA + 1];
    __shared__ float sc[RT][Ssz];            // probs
    __shared__ float Yt[RT][Dm];             // attention output (concat heads)
    __shared__ float opv[2][RT][DA];         // split-K PV partials
    __shared__ float dn[RT];
    __shared__ float xn[RT][Dm];
    __shared__ float yf[RT][4 * Dm];
    int rb = swz16(blockIdx.x, Ssz / RT);
    int b = rb / (Ssz / RT), qt = rb % (Ssz / RT);
    int q0 = qt * RT;
    int row0 = rb * RT;                      // == b*Ssz + q0
    int tid = threadIdx.x;

    for (int i = tid; i < RT * Hh * DA; i += 256) {
        int r = i >> 7, rest = i & 127, h = rest >> 5, e = rest & 31;
        q[r][h][e] = p.Q[((size_t)(b * Hh + h) * Ssz + q0 + r) * DA + e];
    }
    const float scale = 0.17677669529663689f;   // 1/sqrt(32)

    for (int h = 0; h < Hh; h++) {
        __syncthreads();   // protect Kh/Vh (prev head) and q (first iter)
        {
            const float4* K4 = (const float4*)(p.K + ((size_t)(b * Hh + h) * Ssz) * DA);
            const float4* V4 = (const float4*)(p.V + ((size_t)(b * Hh + h) * Ssz) * DA);
            for (int i = tid; i < Ssz * DA / 4; i += 256) {
                float4 kv = K4[i], vv = V4[i];
                int k = i >> 3, e0 = (i & 7) * 4;
                Kh[k][e0] = kv.x; Kh[k][e0 + 1] = kv.y; Kh[k][e0 + 2] = kv.z; Kh[k][e0 + 3] = kv.w;
                Vh[k][e0] = vv.x; Vh[k][e0 + 1] = vv.y; Vh[k][e0 + 2] = vv.z; Vh[k][e0 + 3] = vv.w;
            }
        }
        __syncthreads();
        // scores: wave r handles row r, lane c0 covers cols c0, c0+64
        {
            int r = tid >> 6, c0 = tid & 63;
            const float* Bpr = p.Bp + (((size_t)(l * Bsz + b) * Hh + h) * Ssz + q0 + r) * Ssz;
            float d0 = 0.f, d1 = 0.f;
            bool v1 = (c0 + 64) < Ssz;
            for (int e = 0; e < DA; e++) {
                float qv = q[r][h][e];
                d0 += qv * Kh[c0][e];
                if (v1) d1 += qv * Kh[c0 + 64][e];
            }
            d0 = (d0 + Bpr[c0]) * scale;
            d1 = v1 ? (d1 + Bpr[c0 + 64]) * scale : -1e30f;
            float m = fmaxf(d0, d1);
#pragma unroll
            for (int off = 32; off; off >>= 1) m = fmaxf(m, __shfl_xor(m, off));
            float p0 = expf(d0 - m);
            float p1 = v1 ? expf(d1 - m) : 0.f;
            float s = p0 + p1;
#pragma unroll
            for (int off = 32; off; off >>= 1) s += __shfl_xor(s, off);
            sc[r][c0] = p0;
            if (v1) sc[r][c0 + 64] = p1;
            if (c0 == 0) dn[r] = s;
        }
        __syncthreads();
        // PV, split-K in halves of 60
        {
            int half = tid >> 7, r = (tid >> 5) & 3, m = tid & 31;
            float a = 0.f;
            int k0 = half * 60;
            for (int k = k0; k < k0 + 60; k++) a += sc[r][k] * Vh[k][m];
            opv[half][r][m] = a;
        }
        __syncthreads();
        if (tid < 128) {
            int r = (tid >> 5) & 3, m = tid & 31;
            Yt[r][h * DA + m] = (opv[0][r][m] + opv[1][r][m]) / dn[r];
        }
    }
    __syncthreads();
    // O-proj: rows 2g, 2g+1; keep residual in regs
    int g = tid >> 7, j = tid & 127;
    float xv0, xv1;
    {
        const float* W = p.Wo + l * Dm * Dm + j;
        float a0 = 0.f, a1 = 0.f;
        for (int k = 0; k < Dm; k++) {
            float w = W[k * Dm];
            a0 += Yt[2 * g][k] * w; a1 += Yt[2 * g + 1][k] * w;
        }
        float bb = p.bo[l * Dm + j];
        xv0 = X[(row0 + 2 * g) * Dm + j] + a0 + bb;
        xv1 = X[(row0 + 2 * g + 1) * Dm + j] + a1 + bb;
        xn[2 * g][j] = xv0; xn[2 * g + 1][j] = xv1;
    }
    __syncthreads();
    ln_rows4(xn, xn, p.ln2_s + l * Dm, p.ln2_b + l * Dm, tid);
    __syncthreads();
    // FFN f1: 512 cols in 2 groups of 256
    for (int cg = 0; cg < 2; cg++) {
        int col = cg * 256 + tid;
        const float* W1 = p.f1_w + (size_t)l * Dm * 512 + col;
        float a0 = 0.f, a1 = 0.f, a2 = 0.f, a3 = 0.f;
        for (int i = 0; i < Dm; i++) {
            float w = W1[i * 512];
            a0 += xn[0][i] * w; a1 += xn[1][i] * w; a2 += xn[2][i] * w; a3 += xn[3][i] * w;
        }
        float b1 = p.f1_b[l * 512 + col];
        yf[0][col] = a0 + b1; yf[1][col] = a1 + b1; yf[2][col] = a2 + b1; yf[3][col] = a3 + b1;
    }
    __syncthreads();
    for (int i = tid; i < RT * 256; i += 256) {
        int r = i >> 8, k = i & 255;
        yf[r][k] = gelu_f(yf[r][k]) * yf[r][k + 256];
    }
    __syncthreads();
    {
        const float* W2 = p.f2_w + (size_t)l * 256 * Dm + j;
        float a0 = 0.f, a1 = 0.f;
        for (int k = 0; k < 256; k++) {
            float w = W2[k * Dm];
            a0 += yf[2 * g][k] * w; a1 += yf[2 * g + 1][k] * w;
        }
        float b2 = p.f2_b[l * Dm + j];
        X[(row0 + 2 * g) * Dm + j] = xv0 + a0 + b2;
        X[(row0 + 2 * g + 1) * Dm + j] = xv1 + a1 + b2;
    }
}

// ---- conv(k=3, SAME) over stabilizer axis.  grid 480, 256 thr ----
__global__ __launch_bounds__(256) void k_conv(KParams p, const float* Xin, float* Xout, int l) {
    __shared__ float xr[RT + 2][Dm];
    int rb = swz16(blockIdx.x, Ssz / RT);
    int row0 = rb * RT;
    int b = row0 / Ssz, s0 = row0 % Ssz;
    int tid = threadIdx.x;
    {
        float4* xr4 = (float4*)&xr[0][0];
        for (int i = tid; i < (RT + 2) * Dm / 4; i += 256) {
            int rr = i >> 5, c = i & 31;
            int s = s0 + rr - 1;
            float4 v = make_float4(0.f, 0.f, 0.f, 0.f);
            if (s >= 0 && s < Ssz) v = *(const float4*)(Xin + (b * Ssz + s) * Dm + 4 * c);
            xr4[i] = v;
        }
    }
    __syncthreads();
    int g = tid >> 7, j = tid & 127;
    const float* CW = p.cwT + (size_t)l * Dm * 3 * Dm + j;   // [i][k][o], o=j
    float a0 = 0.f, a1 = 0.f;
    for (int i = 0; i < Dm; i++) {
        float w0 = CW[(i * 3 + 0) * Dm];
        float w1 = CW[(i * 3 + 1) * Dm];
        float w2 = CW[(i * 3 + 2) * Dm];
        a0 += w0 * xr[2 * g][i]     + w1 * xr[2 * g + 1][i] + w2 * xr[2 * g + 2][i];
        a1 += w0 * xr[2 * g + 1][i] + w1 * xr[2 * g + 2][i] + w2 * xr[2 * g + 3][i];
    }
    float cb = p.conv_b[l * Dm + j];
    Xout[(row0 + 2 * g) * Dm + j]     = xr[2 * g + 1][j] + gelu_f(a0 + cb);
    Xout[(row0 + 2 * g + 1) * Dm + j] = xr[2 * g + 2][j] + gelu_f(a1 + cb);
}

// ---- readout: lnf + pad into 12x12 grid.  grid 2304, 128 thr ----
__global__ __launch_bounds__(128) void k_grid(KParams p, const float* X) {
    int blk = swz16(blockIdx.x, 144);
    int b = blk / 144, cell = blk % 144;
    int j = threadIdx.x;
    float* Gr = p.G + (size_t)(b * 144 + cell) * Dm;
    if (cell >= Ssz) { Gr[j] = p.Pp[j]; return; }
    __shared__ float red[4];
    float x = X[(b * Ssz + cell) * Dm + j];
    float s1 = x;
#pragma unroll
    for (int off = 32; off; off >>= 1) s1 += __shfl_xor(s1, off);
    if ((j & 63) == 0) red[j >> 6] = s1;
    __syncthreads();
    float m = (red[0] + red[1]) * (1.f / 128.f);
    float d0 = x - m, s2 = d0 * d0;
#pragma unroll
    for (int off = 32; off; off >>= 1) s2 += __shfl_xor(s2, off);
    if ((j & 63) == 0) red[2 + (j >> 6)] = s2;
    __syncthreads();
    float v = (red[2] + red[3]) * (1.f / 128.f);
    Gr[j] = d0 * rsqrtf(v + 1e-5f) * p.lnf_s[j] + p.lnf_b[j];
}

// ---- scale-conv 2x2/2 + gelu + dim-reduce + gelu -> Y2.  grid 576, 128 thr ----
__global__ __launch_bounds__(128) void k_head(KParams p) {
    int blk = swz16(blockIdx.x, 36);
    int b = blk / 36, r2 = blk % 36, oh = r2 / 6, ow = r2 % 6;
    __shared__ float cells[4][Dm];
    __shared__ float sx[Dm];
    int j = threadIdx.x;
#pragma unroll
    for (int c = 0; c < 4; c++) {
        int kh = c >> 1, kw = c & 1;
        int cell = (2 * oh + kh) * 12 + (2 * ow + kw);
        cells[c][j] = p.G[(size_t)(b * 144 + cell) * Dm + j];
    }
    __syncthreads();
    float acc = p.sc_b[j];
    const float* W = p.sc_w + (size_t)j * Dm * 4;   // [o=j][i][kh][kw]
    for (int i = 0; i < Dm; i++) {
        acc += W[i * 4 + 0] * cells[0][i] + W[i * 4 + 1] * cells[1][i]
             + W[i * 4 + 2] * cells[2][i] + W[i * 4 + 3] * cells[3][i];
    }
    sx[j] = gelu_f(acc);
    __syncthreads();
    if (j < 48) {
        float a = p.dr_b[j];
        const float* w = p.dr_w + j * Dm;
        for (int i = 0; i < Dm; i++) a += sx[i] * w[i];
        p.Y2[((b * 6 + ow) * 6 + oh) * 48 + j] = gelu_f(a);
    }
}

// ---- mean over oh + 16 resblocks + out_w dot ----
__global__ __launch_bounds__(64) void k_rb(KParams p) {
    int blk = blockIdx.x; int b = blk / 6, ow = blk % 6;
    __shared__ float x[48], t[48];
    int j = threadIdx.x;
    if (j < 48) {
        float s = 0.f;
#pragma unroll
        for (int oh = 0; oh < 6; oh++) s += p.Y2[((b * 6 + ow) * 6 + oh) * 48 + j];
        x[j] = s * (1.f / 6.f);
    }
    __syncthreads();
    for (int r = 0; r < 16; r++) {
        if (j < 48) {
            float a = p.rb1_b[r * 48 + j];
            const float* W = p.rb1_w + (size_t)r * 48 * 48 + j;
            for (int i = 0; i < 48; i++) a += x[i] * W[i * 48];
            t[j] = gelu_f(a);
        }
        __syncthreads();
        if (j < 48) {
            float a = p.rb2_b[r * 48 + j];
            const float* W = p.rb2_w + (size_t)r * 48 * 48 + j;
            for (int i = 0; i < 48; i++) a += t[i] * W[i * 48];
            x[j] += a;
        }
        __syncthreads();
    }
    float pr = (j < 48) ? x[j] * p.out_w[j] : 0.f;
#pragma unroll
    for (int off = 32; off; off >>= 1) pr += __shfl_xor(pr, off);
    if (j == 0) p.tmp[b * 6 + ow] = pr + p.out_b[0];
}

__global__ __launch_bounds__(64) void k_final(KParams p, float* out) {
    int b = threadIdx.x;
    if (b < Bsz) {
        float s = 0.f;
#pragma unroll
        for (int w = 0; w < 6; w++) s += p.tmp[b * 6 + w];
        out[b] = s * (1.f / 6.f);
    }
}

extern "C" void kernel_launch(void* const* d_in, const int* in_sizes, int n_in,
                              void* d_out, int out_size, void* d_ws, size_t ws_size,
                              hipStream_t stream) {
    KParams p;
    p.meas       = (const float*)d_in[0];
    p.event_     = (const float*)d_in[1];
    p.leak       = (const float*)d_in[2];
    p.event_leak = (const float*)d_in[3];
    p.bias       = (const float*)d_in[4];
    p.pm_w  = (const float*)d_in[5];  p.pm_b  = (const float*)d_in[6];
    p.pe_w  = (const float*)d_in[7];  p.pe_b  = (const float*)d_in[8];
    p.pl_w  = (const float*)d_in[9];  p.pl_b  = (const float*)d_in[10];
    p.pel_w = (const float*)d_in[11]; p.pel_b = (const float*)d_in[12];
    p.stab_emb = (const float*)d_in[13];
    p.cyc_emb  = (const float*)d_in[14];
    p.er_ln_s  = (const float*)d_in[15]; p.er_ln_b  = (const float*)d_in[16];
    p.er_fc1_w = (const float*)d_in[17]; p.er_fc1_b = (const float*)d_in[18];
    p.er_fc2_w = (const float*)d_in[19]; p.er_fc2_b = (const float*)d_in[20];
    p.ln1_s = (const float*)d_in[21]; p.ln1_b = (const float*)d_in[22];
    p.Wb = (const float*)d_in[23];
    p.Wq = (const float*)d_in[24]; p.bq = (const float*)d_in[25];
    p.Wk = (const float*)d_in[26]; p.bk = (const float*)d_in[27];
    p.Wv = (const float*)d_in[28]; p.bv = (const float*)d_in[29];
    p.Wo = (const float*)d_in[30]; p.bo = (const float*)d_in[31];
    p.ln2_s = (const float*)d_in[32]; p.ln2_b = (const float*)d_in[33];
    p.f1_w = (const float*)d_in[34]; p.f1_b = (const float*)d_in[35];
    p.f2_w = (const float*)d_in[36]; p.f2_b = (const float*)d_in[37];
    p.conv_w = (const float*)d_in[38]; p.conv_b = (const float*)d_in[39];
    p.lnf_s = (const float*)d_in[40]; p.lnf_b = (const float*)d_in[41];
    p.Pp   = (const float*)d_in[42];
    p.sc_w = (const float*)d_in[43]; p.sc_b = (const float*)d_in[44];
    p.dr_w = (const float*)d_in[45]; p.dr_b = (const float*)d_in[46];
    p.rb1_w = (const float*)d_in[47]; p.rb1_b = (const float*)d_in[48];
    p.rb2_w = (const float*)d_in[49]; p.rb2_b = (const float*)d_in[50];
    p.out_w = (const float*)d_in[51]; p.out_b = (const float*)d_in[52];
    p.stab_ids  = (const int*)d_in[53];
    p.cycle_ids = (const int*)d_in[54];

    float* ws = (float*)d_ws;
    size_t off = 0;
    const size_t BP_SZ  = (size_t)Lly * Bsz * Hh * Ssz * Ssz;   // 1,843,200
    const size_t QKV_SZ = (size_t)Bsz * Hh * Ssz * DA;          //   245,760
    const size_t X_SZ   = (size_t)Bsz * Ssz * Dm;               //   245,760
    p.Bp = ws + off; off += BP_SZ;
    p.Q  = ws + off; off += QKV_SZ;
    p.K  = ws + off; off += QKV_SZ;
    p.V  = ws + off; off += QKV_SZ;
    float* X0 = ws + off; off += X_SZ;
    float* X1 = ws + off; off += X_SZ;
    p.G   = ws + off; off += (size_t)Bsz * 144 * Dm;
    p.Y2  = ws + off; off += (size_t)Bsz * 6 * 6 * 48;
    p.tmp = ws + off; off += 96;
    p.cwT = ws + off; off += (size_t)Lly * Dm * 3 * Dm;

    hipMemsetAsync(X0, 0, X_SZ * sizeof(float), stream);
    k_prepcw<<<(Lly * Dm * 3 * Dm + 255) / 256, 256, 0, stream>>>(p);
    k_bias<<<Lly * Bsz * Ssz, 128, 0, stream>>>(p);

    float* Xc = X0;
    float* Xa = X1;
    for (int t = 0; t < Tcy; t++) {
        k_embed<<<NRT, 256, 0, stream>>>(p, Xc, t);
        for (int l = 0; l < Lly; l++) {
            k_qkv<<<NRT, 384, 0, stream>>>(p, Xc, l);
            k_attn_ffn<<<NRT, 256, 0, stream>>>(p, Xc, l);
            k_conv<<<NRT, 256, 0, stream>>>(p, Xc, Xa, l);
            float* tp = Xc; Xc = Xa; Xa = tp;
        }
    }
    k_grid<<<Bsz * 144, 128, 0, stream>>>(p, Xc);
    k_head<<<Bsz * 36, 128, 0, stream>>>(p);
    k_rb<<<Bsz * 6, 64, 0, stream>>>(p);
    k_final<<<1, 64, 0, stream>>>(p, (float*)d_out);
}